// Round 4
// baseline (673.170 us; speedup 1.0000x reference)
//
#include <hip/hip_runtime.h>

// ---------------------------------------------------------------------------
// StructuralCausalModel: 3 layers x 32 vars sequential scan, BATCH=512.
// R4: (a) rotated cross-step weight prefetch: W1/W2/W3 for step i+1 are loaded
// immediately after their last use in step i (register buffer is dead there),
// giving 4-5 stages of latency cover across lgkm-only barriers; small operands
// (emb/bias/NE) double-buffered, loaded during pa; (b) adjacency in LDS;
// (c) coalesced LDS-tiled weight-swizzle prep (old prep was ~16x overfetch);
// (d) cheaper bf16 unpack + 3-term erf. 64 blocks x 512 thr, BTILE=8.
// ---------------------------------------------------------------------------

typedef __bf16 bf16x8 __attribute__((ext_vector_type(8)));
typedef float  f32x4  __attribute__((ext_vector_type(4)));

#define N_VARS 32
#define BTILE 8
#define NBLK 64

// ws element offsets (bf16 region starts at byte 4096; adjT f32 at byte 0)
#define ELOFF_PA 0
#define ELOFF_W1 65536
#define ELOFF_W2 1114112
#define ELOFF_W3 1638400
// total bf16 el = 2686976 -> ws bytes = 4096 + 5373952

__device__ __forceinline__ unsigned short f2b(float f) {
    unsigned u = __float_as_uint(f);
    u += 0x7FFFu + ((u >> 16) & 1u);
    return (unsigned short)(u >> 16);
}

// lgkm-only barrier: LDS ordering enforced, global loads stay in flight.
__device__ __forceinline__ void bar_lds() {
    asm volatile("s_waitcnt lgkmcnt(0)\n\ts_barrier" ::: "memory");
}

// erf via Abramowitz-Stegun 7.1.25, 3 terms (|err| <= 2.5e-5; negligible vs
// bf16 storage rounding which dominates absmax 0.25 / threshold 0.357)
__device__ __forceinline__ float gelu_e(float x) {
    float z  = x * 0.7071067811865476f;
    float az = fabsf(z);
    float t  = __builtin_amdgcn_rcpf(1.0f + 0.47047f * az);
    float p  = t * (0.3480242f + t * (-0.0958798f + t * 0.7478556f));
    float e  = 1.0f - p * __expf(-z * z);
    float er = (z < 0.0f) ? -e : e;
    return 0.5f * x * (1.0f + er);
}

// ---------------------------------------------------------------------------
// Prep (one kernel, 1033 blocks x 256):
//   blocks [0,520): weight swizzle via LDS tile -- coalesced f32 row reads,
//                   coalesced uint4 frag writes (kills the 16x overfetch).
//   block  520    : adjacency adjT[i*32+v] = sigmoid(2*masked_logits[v][i]).
//   blocks [521,1033): noise encoder NE -> d_out (f32), overwritten layer 2.
// B-frag (16x16x32): lane l, elem j -> k = ks*32+(l>>4)*8+j, n = nt*16+(l&15)
// ---------------------------------------------------------------------------
__global__ void prep_all(const float* __restrict__ paW, const float* __restrict__ mW1,
                         const float* __restrict__ mW2, const float* __restrict__ mW3,
                         const float* __restrict__ edge, unsigned short* __restrict__ wsb,
                         float* __restrict__ adjT,
                         const float* __restrict__ noise, const float* __restrict__ neW,
                         const float* __restrict__ neb, float* __restrict__ outp) {
    __shared__ unsigned short tile[32 * 256];
    const int c = blockIdx.x, tid = threadIdx.x;
    if (c < 520) {
        const float* src; unsigned short* dst; int N, KS, ks;
        if (c < 8)        { src = paW;                     dst = wsb + ELOFF_PA;                        N = 256; KS = 8; ks = c; }
        else if (c < 264) { int v = (c - 8) >> 3;   ks = (c - 8) & 7;
                            src = mW1 + v * 32768;         dst = wsb + ELOFF_W1 + v * 32768;            N = 128; KS = 8; }
        else if (c < 392) { int v = (c - 264) >> 2; ks = (c - 264) & 3;
                            src = mW2 + v * 16384;         dst = wsb + ELOFF_W2 + v * 16384;            N = 128; KS = 4; }
        else              { int v = (c - 392) >> 2; ks = (c - 392) & 3;
                            src = mW3 + v * 32768;         dst = wsb + ELOFF_W3 + v * 32768;            N = 256; KS = 4; }
        const int kb = ks * 32, nsh = (N == 256) ? 8 : 7;
        for (int t = tid; t < 32 * N; t += 256) {
            int r = t >> nsh, col = t & (N - 1);
            tile[r * N + col] = f2b(src[(kb + r) * N + col]);   // coalesced in col
        }
        __syncthreads();
        const int nout = (N >> 4) * 64;
        for (int o = tid; o < nout; o += 256) {
            int nt = o >> 6, lane = o & 63;
            int n = nt * 16 + (lane & 15), k0 = (lane >> 4) << 3;
            unsigned e[8];
            #pragma unroll
            for (int j = 0; j < 8; j++) e[j] = tile[(k0 + j) * N + n];
            uint4 pk;
            pk.x = e[0] | (e[1] << 16); pk.y = e[2] | (e[3] << 16);
            pk.z = e[4] | (e[5] << 16); pk.w = e[6] | (e[7] << 16);
            *(uint4*)(dst + ((nt * KS + ks) * 64 + lane) * 8) = pk;   // coalesced
        }
    } else if (c == 520) {
        for (int t = tid; t < 1024; t += 256) {
            int v = t >> 5, ci = t & 31;
            float x = edge[t];
            float m = (v == ci) ? 0.0f : x;   // diag logit masked -> adj diag = 0.5
            adjT[ci * 32 + v] = __builtin_amdgcn_rcpf(1.0f + __expf(-2.0f * m));
        }
    } else {
        int sb = c - 521;                     // 512 sub-blocks: 32 vars x 16 groups
        int i = sb >> 4, g = sb & 15, d = tid;
        float w[64];
        #pragma unroll
        for (int k = 0; k < 64; k++) w[k] = neW[(i * 64 + k) * 256 + d];
        float bias = neb[i * 256 + d];
        for (int bb = 0; bb < 32; bb++) {
            int b = g * 32 + bb;
            const float* nr = noise + (b * 32 + i) * 64;
            float acc = bias;
            #pragma unroll
            for (int k = 0; k < 64; k++) acc += nr[k] * w[k];
            outp[(b * 32 + i) * 256 + d] = gelu_e(acc);
        }
    }
}

#define MFMA16(a, b, c) __builtin_amdgcn_mfma_f32_16x16x32_bf16(a, b, c, 0, 0, 0)

// ---------------------------------------------------------------------------
// Main: 64 blocks x 512 threads, 1 block/CU (LDS 157 KB).
// Flattened 96-step loop; per step: pc -> pa -> W1 -> W2 -> W3, lgkm barriers.
// Weight buffers reloaded for step s+1 right after their last use in step s.
// ---------------------------------------------------------------------------
__global__ __launch_bounds__(512) void
scm_main(const float* __restrict__ emb, const float* __restrict__ pab,
         const float* __restrict__ mb1, const float* __restrict__ mb2,
         const float* __restrict__ mb3, const float* __restrict__ adjT,
         const __bf16* __restrict__ wsbf, float* __restrict__ outp) {
    __shared__ unsigned short valsS[32 * 2048];   // [var][b<8][256 d]  128 KB
    __shared__ unsigned short Xs[16 * 264];
    __shared__ unsigned short X2[16 * 264];
    __shared__ unsigned short Hs1[16 * 136];
    __shared__ unsigned short Hs2[16 * 136];
    __shared__ float adjS[1024];                  // adjT copy (per-step column i*32)

    const int tid = threadIdx.x, blk = blockIdx.x;

    for (int k = tid; k < 16 * 264; k += 512) { Xs[k] = 0; X2[k] = 0; }
    for (int k = tid; k < 16 * 136; k += 512) { Hs1[k] = 0; Hs2[k] = 0; }
    for (int k = tid; k < 1024; k += 512) adjS[k] = adjT[k];
    {
        uint4 z; z.x = z.y = z.z = z.w = 0;
        for (int k = tid; k < 8192; k += 512) ((uint4*)valsS)[k] = z;
    }

    const int wid = tid >> 6, lane = tid & 63, l15 = lane & 15, q = lane >> 4;
    const int nW = wid * 16 + l15;
    const int n0 = nW, n1 = nW + 128;
    const int d4 = lane << 2;

    // step-invariant: pa_W fragments + pa bias resident
    bf16x8 paf0[8], paf1[8];
    #pragma unroll
    for (int ks = 0; ks < 8; ks++) {
        paf0[ks] = *(const bf16x8*)(wsbf + ELOFF_PA + ((wid * 8 + ks) * 64 + lane) * 8);
        paf1[ks] = *(const bf16x8*)(wsbf + ELOFF_PA + (((wid + 8) * 8 + ks) * 64 + lane) * 8);
    }
    const float pb0 = pab[n0], pb1 = pab[n1];

    // preload step 0 operands
    bf16x8 w1f[8], w2f[4], w3f0[4], w3f1[4];
    #pragma unroll
    for (int ks = 0; ks < 8; ks++)
        w1f[ks] = *(const bf16x8*)(wsbf + ELOFF_W1 + ((wid * 8 + ks) * 64 + lane) * 8);
    #pragma unroll
    for (int ks = 0; ks < 4; ks++) {
        w2f[ks]  = *(const bf16x8*)(wsbf + ELOFF_W2 + ((wid * 4 + ks) * 64 + lane) * 8);
        w3f0[ks] = *(const bf16x8*)(wsbf + ELOFF_W3 + ((wid * 4 + ks) * 64 + lane) * 8);
        w3f1[ks] = *(const bf16x8*)(wsbf + ELOFF_W3 + (((wid + 8) * 4 + ks) * 64 + lane) * 8);
    }
    float4 e4 = *(const float4*)(emb + d4);
    float bi1 = mb1[nW], bi2 = mb2[nW], b3a = mb3[n0], b3b = mb3[n1];
    float ne0[4], ne1[4];
    #pragma unroll
    for (int r = 0; r < 4; r++) {
        int mrow = q * 4 + r;
        ne0[r] = 0.f; ne1[r] = 0.f;
        if (mrow < BTILE) {
            size_t ob = ((size_t)(blk * BTILE + mrow) * 32) * 256;
            ne0[r] = outp[ob + n0];
            ne1[r] = outp[ob + n1];
        }
    }
    bar_lds();

    for (int s = 0; s < 3 * N_VARS; s++) {
        const int i = s & 31, ni = (s + 1) & 31;
        const bool last = s >= 64;

        // ---- pc = sum_v adj[v,i]*vals[b,v,:]; X = bf16(pc + emb_i) ----
        {
            float4 av[8];
            #pragma unroll
            for (int g = 0; g < 8; g++) av[g] = *(const float4*)(&adjS[i * 32 + g * 4]);
            float a0 = 0.f, a1 = 0.f, a2 = 0.f, a3 = 0.f;
            const unsigned short* vp = valsS + wid * 256 + d4;
            #pragma unroll
            for (int v = 0; v < 32; v++) {
                uint2 u = *(const uint2*)(vp + v * 2048);
                float sc = ((const float*)av)[v];
                a0 += sc * __uint_as_float(u.x << 16);
                a1 += sc * __uint_as_float(u.x & 0xFFFF0000u);
                a2 += sc * __uint_as_float(u.y << 16);
                a3 += sc * __uint_as_float(u.y & 0xFFFF0000u);
            }
            uint2 w;
            w.x = (unsigned)f2b(a0 + e4.x) | ((unsigned)f2b(a1 + e4.y) << 16);
            w.y = (unsigned)f2b(a2 + e4.z) | ((unsigned)f2b(a3 + e4.w) << 16);
            *(uint2*)(Xs + wid * 264 + d4) = w;
        }
        bar_lds();

        // ---- pa stage; first issue next-step small-operand prefetch ----
        float4 e4n = *(const float4*)(emb + ni * 256 + d4);
        float bi1n = mb1[ni * 128 + nW];
        float bi2n = mb2[ni * 128 + nW];
        float b3an = mb3[ni * 256 + n0];
        float b3bn = mb3[ni * 256 + n1];
        float ne0n[4], ne1n[4];
        #pragma unroll
        for (int r = 0; r < 4; r++) {
            int mrow = q * 4 + r;
            ne0n[r] = 0.f; ne1n[r] = 0.f;
            if (mrow < BTILE) {
                size_t ob = ((size_t)(blk * BTILE + mrow) * 32 + ni) * 256;
                ne0n[r] = outp[ob + n0];
                ne1n[r] = outp[ob + n1];
            }
        }
        {
            f32x4 acc0 = {0, 0, 0, 0}, acc1 = {0, 0, 0, 0};
            #pragma unroll
            for (int ks = 0; ks < 8; ks++) {
                bf16x8 af = *(const bf16x8*)(Xs + l15 * 264 + ks * 32 + q * 8);
                acc0 = MFMA16(af, paf0[ks], acc0);
                acc1 = MFMA16(af, paf1[ks], acc1);
            }
            #pragma unroll
            for (int r = 0; r < 4; r++) {
                int mrow = q * 4 + r;
                if (mrow < BTILE) {
                    X2[mrow * 264 + n0] = f2b(gelu_e(acc0[r] + pb0));
                    X2[mrow * 264 + n1] = f2b(gelu_e(acc1[r] + pb1));
                }
            }
        }
        bar_lds();

        // ---- W1: gelu(X2 @ W1 + b1); then reload w1f for step s+1 ----
        {
            f32x4 aa = {0, 0, 0, 0}, ab = {0, 0, 0, 0};
            #pragma unroll
            for (int ks = 0; ks < 8; ks += 2) {
                bf16x8 af0 = *(const bf16x8*)(X2 + l15 * 264 + ks * 32 + q * 8);
                bf16x8 af1 = *(const bf16x8*)(X2 + l15 * 264 + (ks + 1) * 32 + q * 8);
                aa = MFMA16(af0, w1f[ks], aa);
                ab = MFMA16(af1, w1f[ks + 1], ab);
            }
            #pragma unroll
            for (int r = 0; r < 4; r++) {
                int mrow = q * 4 + r;
                if (mrow < BTILE)
                    Hs1[mrow * 136 + nW] = f2b(gelu_e(aa[r] + ab[r] + bi1));
            }
        }
        #pragma unroll
        for (int ks = 0; ks < 8; ks++)
            w1f[ks] = *(const bf16x8*)(wsbf + ELOFF_W1 + (size_t)ni * 32768 +
                                       ((wid * 8 + ks) * 64 + lane) * 8);
        bar_lds();

        // ---- W2: gelu(h1 @ W2 + b2); then reload w2f for step s+1 ----
        {
            f32x4 acc = {0, 0, 0, 0};
            #pragma unroll
            for (int ks = 0; ks < 4; ks++) {
                bf16x8 af = *(const bf16x8*)(Hs1 + l15 * 136 + ks * 32 + q * 8);
                acc = MFMA16(af, w2f[ks], acc);
            }
            #pragma unroll
            for (int r = 0; r < 4; r++) {
                int mrow = q * 4 + r;
                if (mrow < BTILE)
                    Hs2[mrow * 136 + nW] = f2b(gelu_e(acc[r] + bi2));
            }
        }
        #pragma unroll
        for (int ks = 0; ks < 4; ks++)
            w2f[ks] = *(const bf16x8*)(wsbf + ELOFF_W2 + (size_t)ni * 16384 +
                                       ((wid * 4 + ks) * 64 + lane) * 8);
        bar_lds();

        // ---- W3: out = h2 @ W3 + b3 + NE; vals[:,i] = out; reload w3f ----
        {
            f32x4 acc0 = {0, 0, 0, 0}, acc1 = {0, 0, 0, 0};
            #pragma unroll
            for (int ks = 0; ks < 4; ks++) {
                bf16x8 af = *(const bf16x8*)(Hs2 + l15 * 136 + ks * 32 + q * 8);
                acc0 = MFMA16(af, w3f0[ks], acc0);
                acc1 = MFMA16(af, w3f1[ks], acc1);
            }
            #pragma unroll
            for (int r = 0; r < 4; r++) {
                int mrow = q * 4 + r;
                if (mrow < BTILE) {
                    float v0 = acc0[r] + b3a + ne0[r];
                    float v1 = acc1[r] + b3b + ne1[r];
                    valsS[i * 2048 + mrow * 256 + n0] = f2b(v0);
                    valsS[i * 2048 + mrow * 256 + n1] = f2b(v1);
                    if (last) {
                        size_t ob = ((size_t)(blk * BTILE + mrow) * 32 + i) * 256;
                        outp[ob + n0] = v0;
                        outp[ob + n1] = v1;
                    }
                }
            }
        }
        #pragma unroll
        for (int ks = 0; ks < 4; ks++) {
            w3f0[ks] = *(const bf16x8*)(wsbf + ELOFF_W3 + (size_t)ni * 32768 +
                                        ((wid * 4 + ks) * 64 + lane) * 8);
            w3f1[ks] = *(const bf16x8*)(wsbf + ELOFF_W3 + (size_t)ni * 32768 +
                                        (((wid + 8) * 4 + ks) * 64 + lane) * 8);
        }
        bar_lds();

        // rotate small operands
        e4 = e4n; bi1 = bi1n; bi2 = bi2n; b3a = b3an; b3b = b3bn;
        #pragma unroll
        for (int r = 0; r < 4; r++) { ne0[r] = ne0n[r]; ne1[r] = ne1n[r]; }
    }
}

extern "C" void kernel_launch(void* const* d_in, const int* in_sizes, int n_in,
                              void* d_out, int out_size, void* d_ws, size_t ws_size,
                              hipStream_t stream) {
    (void)in_sizes; (void)n_in; (void)out_size; (void)ws_size;
    const float* noise = (const float*)d_in[0];
    const float* edge  = (const float*)d_in[1];
    const float* emb   = (const float*)d_in[2];
    const float* paW   = (const float*)d_in[3];
    const float* pab   = (const float*)d_in[4];
    const float* mW1   = (const float*)d_in[5];
    const float* mb1   = (const float*)d_in[6];
    const float* mW2   = (const float*)d_in[7];
    const float* mb2   = (const float*)d_in[8];
    const float* mW3   = (const float*)d_in[9];
    const float* mb3   = (const float*)d_in[10];
    const float* neW   = (const float*)d_in[11];
    const float* neb   = (const float*)d_in[12];
    float* outp = (float*)d_out;

    float* adjT = (float*)d_ws;
    unsigned short* wsb = (unsigned short*)((char*)d_ws + 4096);

    prep_all<<<1033, 256, 0, stream>>>(paW, mW1, mW2, mW3, edge, wsb, adjT,
                                       noise, neW, neb, outp);
    scm_main<<<NBLK, 512, 0, stream>>>(emb, pab, mb1, mb2, mb3, adjT,
                                       (const __bf16*)wsb, outp);
}